// Round 11
// baseline (252.155 us; speedup 1.0000x reference)
//
#include <hip/hip_runtime.h>
#include <hip/hip_bf16.h>
#include <stdint.h>
#include <string.h>

// B=2, S=2048, D_MODEL=1024, H=16, Dh=64
#define SEQ   2048
#define DM    1024
#define NH    16
#define NB    2

typedef __attribute__((ext_vector_type(8))) short bf16x8;
typedef __attribute__((ext_vector_type(4))) float f32x4;
typedef unsigned short u16;
typedef unsigned int   u32;

__device__ __forceinline__ u16 f2bf(float f) {
    u32 u = __float_as_uint(f);
    u += 0x7FFF + ((u >> 16) & 1);   // RNE
    return (u16)(u >> 16);
}
__device__ __forceinline__ u32 pk2bf(float a, float b) {
    __hip_bfloat162 p = __float22bfloat162_rn(make_float2(a, b));
    u32 u; memcpy(&u, &p, 4); return u;
}
__device__ __forceinline__ float fexp2(float x) {
#if __has_builtin(__builtin_amdgcn_exp2f)
    return __builtin_amdgcn_exp2f(x);
#else
    return exp2f(x);
#endif
}
// exp2 with mask folded in: keep-bit (from inverted mask word) sign-extended
// and ANDed into the result. masked -> exactly 0.0f (== exp2(-1e9) path).
__device__ __forceinline__ float mask_exp2(float s, u32 lsel, int pos) {
#if __has_builtin(__builtin_amdgcn_sbfe)
    u32 keep = (u32)__builtin_amdgcn_sbfe((int)lsel, pos, 1);
#else
    u32 keep = (u32)((int)(lsel << (31 - pos)) >> 31);
#endif
    return __uint_as_float(__float_as_uint(fexp2(s)) & keep);
}
// async global->LDS, 16B/lane; LDS dest = wave-uniform base + lane*16
__device__ __forceinline__ void gl_lds16(const void* g, void* l) {
    __builtin_amdgcn_global_load_lds(
        (const __attribute__((address_space(1))) u32*)g,
        (__attribute__((address_space(3))) u32*)l, 16, 0, 0);
}
// Raw barrier WITHOUT vmcnt(0) drain: wait until only N newest VMEM ops
// remain in flight, then s_barrier. "memory" clobber pins ordering.
__device__ __forceinline__ void wbar_vm3() { asm volatile("s_waitcnt vmcnt(3)\ns_barrier" ::: "memory"); }
__device__ __forceinline__ void wbar_vm4() { asm volatile("s_waitcnt vmcnt(4)\ns_barrier" ::: "memory"); }
__device__ __forceinline__ void vm_drain() { asm volatile("s_waitcnt vmcnt(0)" ::: "memory"); }

// ---------------------------------------------------------------------------
// Merged fp32->bf16 convert + maskpack (one launch; R6-validated -15us).
// bid < 8192: bulk cvt; Wq pre-scaled by 0.125*log2(e) (exp2 domain).
// bid >= 8192: maskpack, 4 ints/thread via uint4 + 4x __ballot.
// Bit layout (ballot-native, consumed by attn): per 64-n tile one u64
// (uint2); halfword i holds bits for n%4==i, bit index = (n%64)>>2.
// ---------------------------------------------------------------------------
struct CvtArgs {
    const float* s[7];
    u16* d[7];
    float scale[7];
    int start[8];
    const int* mask;
    u32* mbits;
};
__global__ __launch_bounds__(256) void cvt_kernel(CvtArgs a) {
    int bid = blockIdx.x;
    int tid = threadIdx.x;
    if (bid >= 8192) {
        int widx = (bid - 8192) * 256 + tid;          // uint4 index
        uint4 v = ((const uint4*)a.mask)[widx];
        unsigned long long b0 = __ballot(v.x != 0);
        unsigned long long b1 = __ballot(v.y != 0);
        unsigned long long b2 = __ballot(v.z != 0);
        unsigned long long b3 = __ballot(v.w != 0);
        int lane = tid & 63;
        if (lane < 4) {
            int sh = lane * 16;
            u32 lo = (u32)((b0 >> sh) & 0xFFFF) | ((u32)((b1 >> sh) & 0xFFFF) << 16);
            u32 hi = (u32)((b2 >> sh) & 0xFFFF) | ((u32)((b3 >> sh) & 0xFFFF) << 16);
            size_t N = (size_t)(bid - 8192) * 1024 + (size_t)(tid >> 6) * 256
                     + (size_t)lane * 64;             // global element index
            u32* dst = a.mbits + ((N >> 11) * 64 + ((N >> 6) & 31) * 2);
            *(uint2*)dst = make_uint2(lo, hi);
        }
        return;
    }
    int seg = 0;
#pragma unroll
    for (int i = 1; i < 7; ++i) if (bid >= a.start[i]) seg = i;
    float sc = a.scale[seg];
    size_t base = (size_t)(bid - a.start[seg]) * 2048 + tid * 8;
    const float4* s4 = (const float4*)(a.s[seg] + base);
    float4 x = s4[0], y = s4[1];
    u32 r[4];
    r[0] = pk2bf(x.x*sc, x.y*sc); r[1] = pk2bf(x.z*sc, x.w*sc);
    r[2] = pk2bf(y.x*sc, y.y*sc); r[3] = pk2bf(y.z*sc, y.w*sc);
    *(uint4*)(a.d[seg] + base) = *(uint4*)r;
}

// ---------------------------------------------------------------------------
// bf16 GEMM: Y[r][c] = sum_k A[r][k]*B[c][k], K=1024, BK=32.
// Triple-buffered LDS, prefetch distance 2, raw-barrier pipeline (no vmcnt(0)
// drains inside the loop). XOR swizzle (4 chunks/row) for conflict-free b128.
// RT=4: 128x128 tile; RT=2: 64x128. 256 threads, waves 2x2.
// mode 0: bf16 (B,H,S,64); mode 1: bf16 (B,H,64,S) with sigma column perm
// (within each 64-col block) so attn's PV V-fragments are b128-contiguous;
// mode 2: fp32 row-major.
// [R8-R10 lesson: XCD swizzles on these grids are neutral-to-negative —
//  all operands are L3-resident (m160 caveat). Plain dispatch kept.]
// ---------------------------------------------------------------------------
template<int RT>
__device__ __forceinline__ void gemm_body(const u16* __restrict__ A,
                                          const u16* __restrict__ Bm,
                                          void* __restrict__ Y,
                                          int rtile, int ctile, int mode,
                                          u16* sA, u16* sB) {
    constexpr int ABUF = RT * 32 * 32;          // u16 per A buffer
    constexpr int BBUF = 128 * 32;
    const int tid  = threadIdx.x;
    const int wv   = tid >> 6, lane = tid & 63;
    const int quad = lane >> 4, ln = lane & 15;
    const int wr   = wv >> 1,  wc  = wv & 1;

    const int lr4 = lane >> 2;                          // row in 16-row shot
    const int lcc = ((lane & 3) ^ ((lane >> 3) & 3)) * 8;  // swizzled src col

    const u16* gA[RT/2]; u16* lA[RT/2];
#pragma unroll
    for (int s = 0; s < RT/2; ++s) {
        int seg = wv * (RT/2) + s;
        gA[s] = A + (size_t)(rtile * (RT*32) + seg*16 + lr4) * 1024 + lcc;
        lA[s] = sA + seg * 512;
    }
    const u16* gB[2]; u16* lB[2];
#pragma unroll
    for (int s = 0; s < 2; ++s) {
        int seg = wv * 2 + s;
        gB[s] = Bm + (size_t)(ctile * 128 + seg*16 + lr4) * 1024 + lcc;
        lB[s] = sB + seg * 512;
    }

    f32x4 acc[RT][4];
#pragma unroll
    for (int i = 0; i < RT; ++i)
#pragma unroll
        for (int j = 0; j < 4; ++j) acc[i][j] = (f32x4){0.f,0.f,0.f,0.f};

    const int c0 = (quad ^ ((ln >> 1) & 3)) * 8;

    // prologue: stage kt=0 -> buf0, kt=1 -> buf1
#pragma unroll
    for (int s = 0; s < RT/2; ++s) gl_lds16(gA[s], lA[s]);
#pragma unroll
    for (int s = 0; s < 2; ++s)    gl_lds16(gB[s], lB[s]);
#pragma unroll
    for (int s = 0; s < RT/2; ++s) gl_lds16(gA[s] + 32, lA[s] + ABUF);
#pragma unroll
    for (int s = 0; s < 2; ++s)    gl_lds16(gB[s] + 32, lB[s] + BBUF);

    int bc = 0, bp = 2;
    for (int kt = 0; kt < 32; ++kt) {
        if (RT == 4) wbar_vm4(); else wbar_vm3();   // drain kt's loads only
        int pk = (kt + 2) & 31;                     // wrap keeps waitcnt uniform
#pragma unroll
        for (int s = 0; s < RT/2; ++s) gl_lds16(gA[s] + pk*32, lA[s] + bp*ABUF);
#pragma unroll
        for (int s = 0; s < 2; ++s)    gl_lds16(gB[s] + pk*32, lB[s] + bp*BBUF);

        const u16* sAb = sA + bc * ABUF;
        const u16* sBb = sB + bc * BBUF;
        bf16x8 af[RT], bfr[4];
#pragma unroll
        for (int rt = 0; rt < RT; ++rt)
            af[rt] = *(const bf16x8*)(sAb + (wr*(RT*16) + rt*16 + ln) * 32 + c0);
#pragma unroll
        for (int ct = 0; ct < 4; ++ct)
            bfr[ct] = *(const bf16x8*)(sBb + (wc*64 + ct*16 + ln) * 32 + c0);
#pragma unroll
        for (int rt = 0; rt < RT; ++rt)
#pragma unroll
            for (int ct = 0; ct < 4; ++ct)
                acc[rt][ct] = __builtin_amdgcn_mfma_f32_16x16x32_bf16(
                    af[rt], bfr[ct], acc[rt][ct], 0, 0, 0);

        bc = (bc == 2) ? 0 : bc + 1;
        bp = (bp == 2) ? 0 : bp + 1;
    }
    vm_drain();   // in-flight gl_lds must not land after LDS is reallocated

#pragma unroll
    for (int rt = 0; rt < RT; ++rt) {
#pragma unroll
        for (int ct = 0; ct < 4; ++ct) {
#pragma unroll
            for (int i = 0; i < 4; ++i) {
                int R = rtile*(RT*32) + wr*(RT*16) + rt*16 + quad*4 + i;
                int C = ctile*128 + wc*64 + ct*16 + ln;
                float val = acc[rt][ct][i];
                if (mode == 0) {
                    int b = R >> 11, s = R & 2047, h = C >> 6, d = C & 63;
                    ((u16*)Y)[((size_t)((b*NH + h) * SEQ + s) << 6) + d] = f2bf(val);
                } else if (mode == 1) {
                    int h = R >> 6, d = R & 63, b = C >> 11, n = C & 2047;
                    // sigma column perm within each 64-col block: position
                    // p = q*8+j holds n = (j<4 ? q*4+j : 16+q*4+j-4) (+32 hi)
                    int nl = n & 63;
                    int np = (nl & 32) | (((nl & 15) >> 2) << 3) | (nl & 3)
                           | ((nl & 16) >> 2);
                    n = (n & ~63) | np;
                    ((u16*)Y)[((size_t)((b*NH + h) * 64 + d) << 11) + n] = f2bf(val);
                } else {
                    ((float*)Y)[(size_t)R * 1024 + C] = val;
                }
            }
        }
    }
}

struct QKVArgs { const u16* A[3]; const u16* B[3]; u16* Y[3]; };

// R6-proven dispatch: 3-D grid (32, 8, 3), plain order.
__global__ __launch_bounds__(256) void gemm_qkv(QKVArgs g) {
    __shared__ u16 sA[3 * 128 * 32];
    __shared__ u16 sB[3 * 128 * 32];
    int z = blockIdx.z;
    if (z == 2)
        gemm_body<4>(g.A[2], g.B[2], g.Y[2], blockIdx.y, blockIdx.x, 1, sA, sB);
    else
        gemm_body<4>(g.A[z], g.B[z], g.Y[z], blockIdx.x, blockIdx.y, 0, sA, sB);
}

// RT=2 64x128 tile, 512 blocks = 2 blocks/CU (R9: RT=4 at 1 block/CU loses
// cross-block MFMA/VALU overlap, m114). R6-proven plain 2-D dispatch.
__global__ __launch_bounds__(256) void gemm_out(const u16* __restrict__ A,
                                                const u16* __restrict__ Bm,
                                                float* __restrict__ Y) {
    __shared__ u16 sA[3 * 64 * 32];
    __shared__ u16 sB[3 * 128 * 32];
    gemm_body<2>(A, Bm, Y, blockIdx.x, blockIdx.y, 2, sA, sB);
}

// ---------------------------------------------------------------------------
// Flash attention v10: in-register P + producer-permuted V + 4m x 2n wave
// split. [R8: equal to v8 -> attn is VALU/issue-bound, not LDS-bound. Best
// measured variant (66.5-67.2us, 0 bank conflicts); FROZEN.]
// Per-iter VMEM = {K,V,mask0,mask1}, prefetch dist 2 -> raw barrier vmcnt(4).
// LDS: K 4x8KB | V 4x8KB = 64KB (combine reuses it after drain+sync).
// ---------------------------------------------------------------------------
__global__ __launch_bounds__(512, 4) void attn_kernel(
    const u16* __restrict__ qw,
    const u16* __restrict__ kw,
    const u16* __restrict__ vt,
    const u32* __restrict__ mbits,
    u16* __restrict__ ctx) {

    __shared__ __align__(16) u16 smem[32768];   // 64 KB: K bufs | V bufs
    u16* sK = smem;                              // bufs at bc*4096 (u16)
    u16* sV = smem + 16384;                      // byte 32768

    const int mtile = blockIdx.x;           // 0..15 (128 m-rows each)
    const int bh    = blockIdx.y;           // 0..31
    const int b     = bh >> 4;
    const int tid   = threadIdx.x;
    const int wv    = tid >> 6, lane = tid & 63;
    const int quad  = lane >> 4, ln = lane & 15;
    const int g     = wv >> 2;              // n-half: 0 -> n 0..31, 1 -> 32..63
    const int w2    = wv & 3;               // m-group (32 rows each)
    const int m0    = mtile * 128;

    const size_t hbase = (size_t)bh * SEQ * 64;

    // Q fragments (B operand of S^T): rows m = m0 + w2*32 + mt*16 + ln
    bf16x8 qf[2][2];
#pragma unroll
    for (int mt = 0; mt < 2; ++mt) {
        const u16* qp = qw + hbase + (size_t)(m0 + w2*32 + mt*16 + ln) * 64 + quad*8;
        qf[mt][0] = *(const bf16x8*)(qp);
        qf[mt][1] = *(const bf16x8*)(qp + 32);
    }

    f32x4 o[2][4], lsum[2];
#pragma unroll
    for (int mt = 0; mt < 2; ++mt) {
        lsum[mt] = (f32x4){0.f,0.f,0.f,0.f};
#pragma unroll
        for (int j = 0; j < 4; ++j) o[mt][j] = (f32x4){0.f,0.f,0.f,0.f};
    }

    bf16x8 ones;
#pragma unroll
    for (int i = 0; i < 8; ++i) ones[i] = (short)0x3F80;   // bf16 1.0

    const u32* mrow0 = mbits + (size_t)(b*SEQ + m0 + w2*32 + ln) * 64;
    const u32* mrow1 = mrow0 + ((size_t)16 * 64);

    // K/V staging: one 16B shot per thread per tile (512 thr x 16B = 8KB)
    const int lr = lane >> 3;
    const int lc = (lane & 7) ^ lr;                      // XOR-swizzled chunk
    const u16* gK = kw + hbase + (size_t)(wv*8 + lr) * 64 + lc*8;
    const u16* gV = vt + hbase + (size_t)(wv*8 + lr) * SEQ + lc*8;
    u16* lK = sK + wv * 512;
    u16* lV = sV + wv * 512;

    // Per-lane LDS base addresses; all ds_reads fold to base + immediate.
    const int c0 = (quad ^ (ln & 7)) * 8;
    const u16* a1 = smem + ln*64 + c0;          // lo chunk
    const u16* a2 = smem + ln*64 + (c0 ^ 32);   // hi chunk
    const u16* aK1 = a1 + g*2048;               // K rows of this n-half
    const u16* aK2 = a2 + g*2048;
    const u16* aV  = (g ? a2 : a1) + 16384;     // sigma vf for this n-half
    const int  msh = g*8 + quad;                // mask pre-shift

    // prologue: tiles 0 and 1 -> bufs 0, 1 (4 VMEM/tile: K, V, m0, m1)
    gl_lds16(gK, lK);
    gl_lds16(gV, lV);
    uint2 wA0 = *(const uint2*)(mrow0);
    uint2 wA1 = *(const uint2*)(mrow1);
    gl_lds16(gK + 4096, lK + 4096);
    gl_lds16(gV + 64,   lV + 4096);
    uint2 wB0 = *(const uint2*)(mrow0 + 2);
    uint2 wB1 = *(const uint2*)(mrow1 + 2);

    for (int mi = 0; mi < 8; ++mi) {
#pragma unroll
        for (int u = 0; u < 4; ++u) {
            const int bc = u;                 // read buf  = it & 3 = u
            const int wb = (u + 2) & 3;       // write buf = (it+2) & 3
            wbar_vm4();                       // drain tile it's 4 loads only
            int pidx = (mi*4 + u + 2) & 31;   // wrap keeps waitcnt uniform
            gl_lds16(gK + (size_t)pidx * 4096, lK + wb*4096);
            gl_lds16(gV + pidx * 64,           lV + wb*4096);
            uint2 wC0 = *(const uint2*)(mrow0 + pidx*2);
            uint2 wC1 = *(const uint2*)(mrow1 + pidx*2);

            // S^T = K Q^T on this wave's n-half (2 n-tiles x 2 m-tiles)
            f32x4 s4[2][2];
            __builtin_amdgcn_s_setprio(1);
#pragma unroll
            for (int ct2 = 0; ct2 < 2; ++ct2) {
                bf16x8 k0 = *(const bf16x8*)(aK1 + bc*4096 + ct2*1024);
                bf16x8 k1 = *(const bf16x8*)(aK2 + bc*4096 + ct2*1024);
#pragma unroll
                for (int mt = 0; mt < 2; ++mt) {
                    f32x4 z = (f32x4){0.f, 0.f, 0.f, 0.f};
                    z = __builtin_amdgcn_mfma_f32_16x16x32_bf16(k0, qf[mt][0], z, 0, 0, 0);
                    z = __builtin_amdgcn_mfma_f32_16x16x32_bf16(k1, qf[mt][1], z, 0, 0, 0);
                    s4[mt][ct2] = z;
                }
            }
            __builtin_amdgcn_s_setprio(0);

            // p = exp2(s) & keep-mask -> one packed bf16 P fragment per mt.
            // ballot-native mask: bit pos = (i&1)*16 + ct2*4 of
            // (word >> (g*8 + quad)); word = wA.x for i<2, wA.y for i>=2.
            bf16x8 pfm[2];
#pragma unroll
            for (int mt = 0; mt < 2; ++mt) {
                u32 wx = mt ? wA1.x : wA0.x;
                u32 wy = mt ? wA1.y : wA0.y;
                u32 l0 = ~(wx >> msh);
                u32 l1 = ~(wy >> msh);
                u32 P[4];
#pragma unroll
                for (int ct2 = 0; ct2 < 2; ++ct2) {
                    float p[4];
                    p[0] = mask_exp2(s4[mt][ct2][0], l0, ct2*4);
                    p[1] = mask_exp2(s4[mt][ct2][1], l0, 16 + ct2*4);
                    p[2] = mask_exp2(s4[mt][ct2][2], l1, ct2*4);
                    p[3] = mask_exp2(s4[mt][ct2][3], l1, 16 + ct2*4);
                    P[ct2*2]     = pk2bf(p[0], p[1]);
                    P[ct2*2 + 1] = pk2bf(p[2], p[3]);
                }
                memcpy(&pfm[mt], P, 16);
            }

            // O += P V ; lsum += P * ones. V frag loaded ONCE per ct,
            // shared by both m-tiles (sigma-matched b128, conflict-free).
            __builtin_amdgcn_s_setprio(1);
            lsum[0] = __builtin_amdgcn_mfma_f32_16x16x32_bf16(pfm[0], ones, lsum[0], 0, 0, 0);
            lsum[1] = __builtin_amdgcn_mfma_f32_16x16x32_bf16(pfm[1], ones, lsum[1], 0, 0, 0);
#pragma unroll
            for (int ct = 0; ct < 4; ++ct) {
                bf16x8 vf = *(const bf16x8*)(aV + bc*4096 + ct*1024);
                o[0][ct] = __builtin_amdgcn_mfma_f32_16x16x32_bf16(pfm[0], vf, o[0][ct], 0, 0, 0);
                o[1][ct] = __builtin_amdgcn_mfma_f32_16x16x32_bf16(pfm[1], vf, o[1][ct], 0, 0, 0);
            }
            __builtin_amdgcn_s_setprio(0);

            wA0 = wB0; wA1 = wB1;
            wB0 = wC0; wB1 = wC1;
        }
    }
    vm_drain();       // in-flight gl_lds must not land after LDS is reused
    __syncthreads();  // all waves done with sK/sV before reuse as sO

    // n-half combine: g==1 writes partial O (pitch 68) + lsum; g==0 sums,
    // normalizes, stores. One-time cost.
    float* sO  = (float*)smem;                  // 128 x 68 fp32 = 34816 B
    float* sLs = (float*)((char*)smem + 34816); // 128 fp32
    if (g == 1) {
#pragma unroll
        for (int mt = 0; mt < 2; ++mt)
#pragma unroll
            for (int i = 0; i < 4; ++i) {
                int lm = w2*32 + mt*16 + quad*4 + i;
                sLs[lm] = lsum[mt][i];
#pragma unroll
                for (int ct = 0; ct < 4; ++ct)
                    sO[lm*68 + ct*16 + ln] = o[mt][ct][i];
            }
    }
    __syncthreads();
    if (g == 0) {
#pragma unroll
        for (int mt = 0; mt < 2; ++mt)
#pragma unroll
            for (int i = 0; i < 4; ++i) {
                int lm = w2*32 + mt*16 + quad*4 + i;
                float inv = 1.f / (lsum[mt][i] + sLs[lm]);
                int m = m0 + lm;
                size_t base = ((size_t)(b * SEQ + m) << 10) + (bh & 15) * 64;
#pragma unroll
                for (int ct = 0; ct < 4; ++ct)
                    ctx[base + ct*16 + ln] =
                        f2bf((o[mt][ct][i] + sO[lm*68 + ct*16 + ln]) * inv);
            }
    }
}

// ---------------------------------------------------------------------------
extern "C" void kernel_launch(void* const* d_in, const int* in_sizes, int n_in,
                              void* d_out, int out_size, void* d_ws, size_t ws_size,
                              hipStream_t stream) {
    const float* q    = (const float*)d_in[0];
    const float* k    = (const float*)d_in[1];
    const float* v    = (const float*)d_in[2];
    const int*   mask = (const int*)d_in[3];
    const float* Wq   = (const float*)d_in[4];
    const float* Wk   = (const float*)d_in[5];
    const float* Wv   = (const float*)d_in[6];
    const float* Wo   = (const float*)d_in[7];
    float* out = (float*)d_out;

    char* ws = (char*)d_ws;
    const size_t SZH = (size_t)NB * SEQ * DM * 2;       // 8 MiB
    const size_t SZW = (size_t)DM * DM * 2;             // 2 MiB
    u16* qw   = (u16*)(ws);
    u16* kw   = (u16*)(ws + SZH);
    u16* vt   = (u16*)(ws + 2*SZH);
    u16* ctx  = (u16*)(ws + 3*SZH);
    u16* vb   = ctx;                                    // v bf16 (dead before ctx)
    u32* mbits= (u32*)(ws + 4*SZH);                     // 1 MiB
    u16* qb   = (u16*)(ws + 4*SZH + (1u<<20));
    u16* kb   = (u16*)(ws + 4*SZH + (1u<<20) + SZH);
    u16* Wqb  = (u16*)(ws + 4*SZH + (1u<<20) + 2*SZH);
    u16* Wkb  = (u16*)((char*)Wqb + SZW);
    u16* Wvb  = (u16*)((char*)Wqb + 2*SZW);
    u16* Wob  = (u16*)((char*)Wqb + 3*SZW);

    const float CSC = 0.18033688011112042f;             // 0.125 * log2(e)

    CvtArgs ca;
    ca.s[0]=q;  ca.d[0]=qb;  ca.scale[0]=1.f;
    ca.s[1]=k;  ca.d[1]=kb;  ca.scale[1]=1.f;
    ca.s[2]=v;  ca.d[2]=vb;  ca.scale[2]=1.f;
    ca.s[3]=Wq; ca.d[3]=Wqb; ca.scale[3]=CSC;
    ca.s[4]=Wk; ca.d[4]=Wkb; ca.scale[4]=1.f;
    ca.s[5]=Wv; ca.d[5]=Wvb; ca.scale[5]=1.f;
    ca.s[6]=Wo; ca.d[6]=Wob; ca.scale[6]=1.f;
    int st[8] = {0, 2048, 4096, 6144, 6656, 7168, 7680, 8192};
    for (int i = 0; i < 8; ++i) ca.start[i] = st[i];
    ca.mask  = mask;
    ca.mbits = mbits;
    // merged cvt (bid<8192) + maskpack (bid>=8192, 4 ints/thread)
    cvt_kernel<<<dim3(16384), dim3(256), 0, stream>>>(ca);

    QKVArgs ga;
    ga.A[0]=qb;  ga.B[0]=Wqb; ga.Y[0]=qw;
    ga.A[1]=kb;  ga.B[1]=Wkb; ga.Y[1]=kw;
    ga.A[2]=Wvb; ga.B[2]=vb;  ga.Y[2]=vt;
    gemm_qkv<<<dim3(32, 8, 3), dim3(256), 0, stream>>>(ga);

    attn_kernel<<<dim3(SEQ/128, NB*NH), dim3(512), 0, stream>>>(qw, kw, vt, mbits, ctx);

    gemm_out<<<dim3(64, 8), dim3(256), 0, stream>>>(ctx, Wob, out);
}

// Round 12
// 245.534 us; speedup vs baseline: 1.0270x; 1.0270x over previous
//
#include <hip/hip_runtime.h>
#include <hip/hip_bf16.h>
#include <stdint.h>
#include <string.h>

// B=2, S=2048, D_MODEL=1024, H=16, Dh=64
#define SEQ   2048
#define DM    1024
#define NH    16
#define NB    2

typedef __attribute__((ext_vector_type(8))) short bf16x8;
typedef __attribute__((ext_vector_type(4))) float f32x4;
typedef unsigned short u16;
typedef unsigned int   u32;

__device__ __forceinline__ u16 f2bf(float f) {
    u32 u = __float_as_uint(f);
    u += 0x7FFF + ((u >> 16) & 1);   // RNE
    return (u16)(u >> 16);
}
__device__ __forceinline__ u32 pk2bf(float a, float b) {
    __hip_bfloat162 p = __float22bfloat162_rn(make_float2(a, b));
    u32 u; memcpy(&u, &p, 4); return u;
}
__device__ __forceinline__ float fexp2(float x) {
#if __has_builtin(__builtin_amdgcn_exp2f)
    return __builtin_amdgcn_exp2f(x);
#else
    return exp2f(x);
#endif
}
// exp2 with mask folded in: keep-bit (from inverted mask word) sign-extended
// and ANDed into the result. masked -> exactly 0.0f (== exp2(-1e9) path).
__device__ __forceinline__ float mask_exp2(float s, u32 lsel, int pos) {
#if __has_builtin(__builtin_amdgcn_sbfe)
    u32 keep = (u32)__builtin_amdgcn_sbfe((int)lsel, pos, 1);
#else
    u32 keep = (u32)((int)(lsel << (31 - pos)) >> 31);
#endif
    return __uint_as_float(__float_as_uint(fexp2(s)) & keep);
}
// async global->LDS, 16B/lane; LDS dest = wave-uniform base + lane*16
__device__ __forceinline__ void gl_lds16(const void* g, void* l) {
    __builtin_amdgcn_global_load_lds(
        (const __attribute__((address_space(1))) u32*)g,
        (__attribute__((address_space(3))) u32*)l, 16, 0, 0);
}
// Raw barrier WITHOUT vmcnt(0) drain: wait until only N newest VMEM ops
// remain in flight, then s_barrier. "memory" clobber pins ordering.
__device__ __forceinline__ void wbar_vm2() { asm volatile("s_waitcnt vmcnt(2)\ns_barrier" ::: "memory"); }
__device__ __forceinline__ void wbar_vm3() { asm volatile("s_waitcnt vmcnt(3)\ns_barrier" ::: "memory"); }
__device__ __forceinline__ void wbar_vm4() { asm volatile("s_waitcnt vmcnt(4)\ns_barrier" ::: "memory"); }
__device__ __forceinline__ void bar()      { asm volatile("s_barrier" ::: "memory"); }
__device__ __forceinline__ void vm_drain() { asm volatile("s_waitcnt vmcnt(0)" ::: "memory"); }

// ---------------------------------------------------------------------------
// Merged fp32->bf16 convert + maskpack (one launch; R6-validated -15us).
// bid < 8192: bulk cvt; Wq pre-scaled by 0.125*log2(e) (exp2 domain).
// bid >= 8192: maskpack, 4 ints/thread via uint4 + 4x __ballot.
// Bit layout (ballot-native, consumed by attn): per 64-n tile one u64
// (uint2); halfword i holds bits for n%4==i, bit index = (n%64)>>2.
// ---------------------------------------------------------------------------
struct CvtArgs {
    const float* s[7];
    u16* d[7];
    float scale[7];
    int start[8];
    const int* mask;
    u32* mbits;
};
__global__ __launch_bounds__(256) void cvt_kernel(CvtArgs a) {
    int bid = blockIdx.x;
    int tid = threadIdx.x;
    if (bid >= 8192) {
        int widx = (bid - 8192) * 256 + tid;          // uint4 index
        uint4 v = ((const uint4*)a.mask)[widx];
        unsigned long long b0 = __ballot(v.x != 0);
        unsigned long long b1 = __ballot(v.y != 0);
        unsigned long long b2 = __ballot(v.z != 0);
        unsigned long long b3 = __ballot(v.w != 0);
        int lane = tid & 63;
        if (lane < 4) {
            int sh = lane * 16;
            u32 lo = (u32)((b0 >> sh) & 0xFFFF) | ((u32)((b1 >> sh) & 0xFFFF) << 16);
            u32 hi = (u32)((b2 >> sh) & 0xFFFF) | ((u32)((b3 >> sh) & 0xFFFF) << 16);
            size_t N = (size_t)(bid - 8192) * 1024 + (size_t)(tid >> 6) * 256
                     + (size_t)lane * 64;             // global element index
            u32* dst = a.mbits + ((N >> 11) * 64 + ((N >> 6) & 31) * 2);
            *(uint2*)dst = make_uint2(lo, hi);
        }
        return;
    }
    int seg = 0;
#pragma unroll
    for (int i = 1; i < 7; ++i) if (bid >= a.start[i]) seg = i;
    float sc = a.scale[seg];
    size_t base = (size_t)(bid - a.start[seg]) * 2048 + tid * 8;
    const float4* s4 = (const float4*)(a.s[seg] + base);
    float4 x = s4[0], y = s4[1];
    u32 r[4];
    r[0] = pk2bf(x.x*sc, x.y*sc); r[1] = pk2bf(x.z*sc, x.w*sc);
    r[2] = pk2bf(y.x*sc, y.y*sc); r[3] = pk2bf(y.z*sc, y.w*sc);
    *(uint4*)(a.d[seg] + base) = *(uint4*)r;
}

// ---------------------------------------------------------------------------
// Legacy bf16 GEMM body (used by gemm_out): Y[r][c] = sum_k A[r][k]*B[c][k],
// K=1024, BK=32. Triple-buffered LDS, prefetch dist 2, raw-barrier counted-
// vmcnt pipeline. RT=2: 64x128 tile, 256 threads.
// mode 2: fp32 row-major output.
// ---------------------------------------------------------------------------
template<int RT>
__device__ __forceinline__ void gemm_body(const u16* __restrict__ A,
                                          const u16* __restrict__ Bm,
                                          void* __restrict__ Y,
                                          int rtile, int ctile, int mode,
                                          u16* sA, u16* sB) {
    constexpr int ABUF = RT * 32 * 32;          // u16 per A buffer
    constexpr int BBUF = 128 * 32;
    const int tid  = threadIdx.x;
    const int wv   = tid >> 6, lane = tid & 63;
    const int quad = lane >> 4, ln = lane & 15;
    const int wr   = wv >> 1,  wc  = wv & 1;

    const int lr4 = lane >> 2;                          // row in 16-row shot
    const int lcc = ((lane & 3) ^ ((lane >> 3) & 3)) * 8;  // swizzled src col

    const u16* gA[RT/2]; u16* lA[RT/2];
#pragma unroll
    for (int s = 0; s < RT/2; ++s) {
        int seg = wv * (RT/2) + s;
        gA[s] = A + (size_t)(rtile * (RT*32) + seg*16 + lr4) * 1024 + lcc;
        lA[s] = sA + seg * 512;
    }
    const u16* gB[2]; u16* lB[2];
#pragma unroll
    for (int s = 0; s < 2; ++s) {
        int seg = wv * 2 + s;
        gB[s] = Bm + (size_t)(ctile * 128 + seg*16 + lr4) * 1024 + lcc;
        lB[s] = sB + seg * 512;
    }

    f32x4 acc[RT][4];
#pragma unroll
    for (int i = 0; i < RT; ++i)
#pragma unroll
        for (int j = 0; j < 4; ++j) acc[i][j] = (f32x4){0.f,0.f,0.f,0.f};

    const int c0 = (quad ^ ((ln >> 1) & 3)) * 8;

    // prologue: stage kt=0 -> buf0, kt=1 -> buf1
#pragma unroll
    for (int s = 0; s < RT/2; ++s) gl_lds16(gA[s], lA[s]);
#pragma unroll
    for (int s = 0; s < 2; ++s)    gl_lds16(gB[s], lB[s]);
#pragma unroll
    for (int s = 0; s < RT/2; ++s) gl_lds16(gA[s] + 32, lA[s] + ABUF);
#pragma unroll
    for (int s = 0; s < 2; ++s)    gl_lds16(gB[s] + 32, lB[s] + BBUF);

    int bc = 0, bp = 2;
    for (int kt = 0; kt < 32; ++kt) {
        if (RT == 4) wbar_vm4(); else wbar_vm3();   // drain kt's loads only
        int pk = (kt + 2) & 31;                     // wrap keeps waitcnt uniform
#pragma unroll
        for (int s = 0; s < RT/2; ++s) gl_lds16(gA[s] + pk*32, lA[s] + bp*ABUF);
#pragma unroll
        for (int s = 0; s < 2; ++s)    gl_lds16(gB[s] + pk*32, lB[s] + bp*BBUF);

        const u16* sAb = sA + bc * ABUF;
        const u16* sBb = sB + bc * BBUF;
        bf16x8 af[RT], bfr[4];
#pragma unroll
        for (int rt = 0; rt < RT; ++rt)
            af[rt] = *(const bf16x8*)(sAb + (wr*(RT*16) + rt*16 + ln) * 32 + c0);
#pragma unroll
        for (int ct = 0; ct < 4; ++ct)
            bfr[ct] = *(const bf16x8*)(sBb + (wc*64 + ct*16 + ln) * 32 + c0);
#pragma unroll
        for (int rt = 0; rt < RT; ++rt)
#pragma unroll
            for (int ct = 0; ct < 4; ++ct)
                acc[rt][ct] = __builtin_amdgcn_mfma_f32_16x16x32_bf16(
                    af[rt], bfr[ct], acc[rt][ct], 0, 0, 0);

        bc = (bc == 2) ? 0 : bc + 1;
        bp = (bp == 2) ? 0 : bp + 1;
    }
    vm_drain();   // in-flight gl_lds must not land after LDS is reallocated

#pragma unroll
    for (int rt = 0; rt < RT; ++rt) {
#pragma unroll
        for (int ct = 0; ct < 4; ++ct) {
#pragma unroll
            for (int i = 0; i < 4; ++i) {
                int R = rtile*(RT*32) + wr*(RT*16) + rt*16 + quad*4 + i;
                int C = ctile*128 + wc*64 + ct*16 + ln;
                float val = acc[rt][ct][i];
                if (mode == 0) {
                    int b = R >> 11, s = R & 2047, h = C >> 6, d = C & 63;
                    ((u16*)Y)[((size_t)((b*NH + h) * SEQ + s) << 6) + d] = f2bf(val);
                } else if (mode == 1) {
                    int h = R >> 6, d = R & 63, b = C >> 11, n = C & 2047;
                    int nl = n & 63;
                    int np = (nl & 32) | (((nl & 15) >> 2) << 3) | (nl & 3)
                           | ((nl & 16) >> 2);
                    n = (n & ~63) | np;
                    ((u16*)Y)[((size_t)((b*NH + h) * 64 + d) << 11) + n] = f2bf(val);
                } else {
                    ((float*)Y)[(size_t)R * 1024 + C] = val;
                }
            }
        }
    }
}

struct QKVArgs { const u16* A[3]; const u16* B[3]; u16* Y[3]; };

// ---------------------------------------------------------------------------
// 256x256 deep-phase qkv GEMM (m201-class schedule, self-derived race-free):
// 512 thr = 8 waves (2M x 4N), BK=64, 2 LDS buffers (128 KB), 4 phases per
// K-tile. Phase p: {stage half-tile p of K-tile kt+1 into the dead buffer |
// p0: vmcnt(2)+barrier (counted drain of kt's 8 loads, never 0); p1-3:
// barrier | p0: 16x ds_read A-frags | 2x ds_read B-frag | setprio(1) 16 MFMA
// setprio(0)}.
// Race-freedom: (a) p0's stage (A-h0 region) overlaps only stragglers reading
// B-regions of the dead buffer (disjoint); (b) p1-3 stages issue after a
// barrier transitively ordering ALL reads of the dead buffer; (c) vmcnt(2)
// after issuing 2 new loads drains exactly the incoming tile's 8.
// Swizzle: phys chunk = logical ^ (row&7) on the 8-chunk/128B row (same
// involution staged via pre-swizzled global source, read via XOR'd col) ->
// 16-lane row-column reads land 2-way (free, m136).
// ---------------------------------------------------------------------------
__global__ __launch_bounds__(512, 2) void gemm_qkv256(QKVArgs g) {
    __shared__ __align__(16) u16 smem[65536];   // 128 KB: 2 x {Ah0,Ah1,Bh0,Bh1}

    const int z  = blockIdx.y;
    const int bx = blockIdx.x;
    int rtile, ctile, mode;
    if (z == 2) { rtile = bx & 3;  ctile = bx >> 2; mode = 1; }
    else        { rtile = bx >> 2; ctile = bx & 3;  mode = 0; }
    const u16* Aa = g.A[z];
    const u16* Ba = g.B[z];
    u16*       Yy = g.Y[z];

    const int tid  = threadIdx.x;
    const int wv   = tid >> 6, lane = tid & 63;
    const int quad = lane >> 4, ln = lane & 15;
    const int wr   = wv >> 2,  wc  = wv & 3;     // 2M x 4N waves

    // staging sources: thread t covers phys chunks t and t+512 of each
    // 16KB half-tile; logical col chunk = (t&7) ^ (row&7) (involution).
    const int r0  = tid >> 3;                    // row 0..63 (load1: +64)
    const int lcq = ((tid & 7) ^ (r0 & 7)) * 8;  // u16 col offset
    const u16* srcs[4];
    srcs[0] = Aa + (size_t)(rtile*256 +       r0) * 1024 + lcq;   // A h0
    srcs[1] = Aa + (size_t)(rtile*256 + 128 + r0) * 1024 + lcq;   // A h1
    srcs[2] = Ba + (size_t)(ctile*256 +       r0) * 1024 + lcq;   // B h0
    srcs[3] = Ba + (size_t)(ctile*256 + 128 + r0) * 1024 + lcq;   // B h1

    // read pointers: phys col = (ks*32 + quad*8) ^ ((ln&7)<<3)  [u16]
    const int sw3 = (ln & 7) << 3;
    const int cs0 = (quad * 8) ^ sw3;
    const int cs1 = (32 + quad * 8) ^ sw3;
    const u16* aA  = smem + wr*8192 + ln*64 + cs0;
    const u16* aA2 = smem + wr*8192 + ln*64 + cs1;
    const u16* bB  = smem + 16384 + (wc>>1)*8192 + (wc&1)*4096 + ln*64 + cs0;
    const u16* bB2 = smem + 16384 + (wc>>1)*8192 + (wc&1)*4096 + ln*64 + cs1;

    f32x4 acc[8][4];
#pragma unroll
    for (int i = 0; i < 8; ++i)
#pragma unroll
        for (int j = 0; j < 4; ++j) acc[i][j] = (f32x4){0.f,0.f,0.f,0.f};

    // prologue: K-tile 0 -> buf0 (4 half-tiles x 2 loads)
#pragma unroll
    for (int p = 0; p < 4; ++p) {
        u16* dst = smem + p*8192 + wv*512;
        gl_lds16(srcs[p], dst);
        gl_lds16(srcs[p] + 65536, dst + 4096);
    }

    for (int kt = 0; kt < 16; ++kt) {
        const int D  = (kt & 1) << 15;           // read buffer (u16 offset)
        const int Dp = D ^ 32768;                // write buffer
        const int pk = (kt + 1) & 15;            // wrap keeps waitcnt uniform
        bf16x8 af[8][2];
#pragma unroll
        for (int p = 0; p < 4; ++p) {
            u16* dst = smem + Dp + p*8192 + wv*512;
            gl_lds16(srcs[p] + pk*64, dst);
            gl_lds16(srcs[p] + pk*64 + 65536, dst + 4096);
            if (p == 0) wbar_vm2(); else bar();
            if (p == 0) {
#pragma unroll
                for (int mf = 0; mf < 8; ++mf) {
                    af[mf][0] = *(const bf16x8*)(aA  + D + mf*1024);
                    af[mf][1] = *(const bf16x8*)(aA2 + D + mf*1024);
                }
            }
            bf16x8 b0 = *(const bf16x8*)(bB  + D + p*1024);
            bf16x8 b1 = *(const bf16x8*)(bB2 + D + p*1024);
            __builtin_amdgcn_s_setprio(1);
#pragma unroll
            for (int mf = 0; mf < 8; ++mf) {
                acc[mf][p] = __builtin_amdgcn_mfma_f32_16x16x32_bf16(
                    af[mf][0], b0, acc[mf][p], 0, 0, 0);
                acc[mf][p] = __builtin_amdgcn_mfma_f32_16x16x32_bf16(
                    af[mf][1], b1, acc[mf][p], 0, 0, 0);
            }
            __builtin_amdgcn_s_setprio(0);
        }
    }
    vm_drain();   // trailing wrap-stages must not outlive the kernel

#pragma unroll
    for (int mf = 0; mf < 8; ++mf)
#pragma unroll
        for (int nf = 0; nf < 4; ++nf)
#pragma unroll
            for (int i = 0; i < 4; ++i) {
                int R = rtile*256 + wr*128 + mf*16 + quad*4 + i;
                int C = ctile*256 + wc*64 + nf*16 + ln;
                float val = acc[mf][nf][i];
                if (mode == 0) {
                    int b = R >> 11, s = R & 2047, h = C >> 6, d = C & 63;
                    Yy[((size_t)((b*NH + h) * SEQ + s) << 6) + d] = f2bf(val);
                } else {
                    int h = R >> 6, d = R & 63, b = C >> 11, n = C & 2047;
                    // sigma column perm within each 64-col block
                    int nl = n & 63;
                    int np = (nl & 32) | (((nl & 15) >> 2) << 3) | (nl & 3)
                           | ((nl & 16) >> 2);
                    n = (n & ~63) | np;
                    Yy[((size_t)((b*NH + h) * 64 + d) << 11) + n] = f2bf(val);
                }
            }
}

// RT=2 64x128 tile, 512 blocks = 2 blocks/CU (R9: RT=4 at 1 block/CU loses
// cross-block MFMA/VALU overlap, m114). R6-proven plain 2-D dispatch.
__global__ __launch_bounds__(256) void gemm_out(const u16* __restrict__ A,
                                                const u16* __restrict__ Bm,
                                                float* __restrict__ Y) {
    __shared__ u16 sA[3 * 64 * 32];
    __shared__ u16 sB[3 * 128 * 32];
    gemm_body<2>(A, Bm, Y, blockIdx.x, blockIdx.y, 2, sA, sB);
}

// ---------------------------------------------------------------------------
// Flash attention v10: in-register P + producer-permuted V + 4m x 2n wave
// split. [R8: equal to v8 -> attn is VALU/issue-bound, not LDS-bound. Best
// measured variant (66.5-67.2us, 0 bank conflicts); FROZEN.]
// Per-iter VMEM = {K,V,mask0,mask1}, prefetch dist 2 -> raw barrier vmcnt(4).
// LDS: K 4x8KB | V 4x8KB = 64KB (combine reuses it after drain+sync).
// ---------------------------------------------------------------------------
__global__ __launch_bounds__(512, 4) void attn_kernel(
    const u16* __restrict__ qw,
    const u16* __restrict__ kw,
    const u16* __restrict__ vt,
    const u32* __restrict__ mbits,
    u16* __restrict__ ctx) {

    __shared__ __align__(16) u16 smem[32768];   // 64 KB: K bufs | V bufs
    u16* sK = smem;                              // bufs at bc*4096 (u16)
    u16* sV = smem + 16384;                      // byte 32768

    const int mtile = blockIdx.x;           // 0..15 (128 m-rows each)
    const int bh    = blockIdx.y;           // 0..31
    const int b     = bh >> 4;
    const int tid   = threadIdx.x;
    const int wv    = tid >> 6, lane = tid & 63;
    const int quad  = lane >> 4, ln = lane & 15;
    const int g     = wv >> 2;              // n-half: 0 -> n 0..31, 1 -> 32..63
    const int w2    = wv & 3;               // m-group (32 rows each)
    const int m0    = mtile * 128;

    const size_t hbase = (size_t)bh * SEQ * 64;

    // Q fragments (B operand of S^T): rows m = m0 + w2*32 + mt*16 + ln
    bf16x8 qf[2][2];
#pragma unroll
    for (int mt = 0; mt < 2; ++mt) {
        const u16* qp = qw + hbase + (size_t)(m0 + w2*32 + mt*16 + ln) * 64 + quad*8;
        qf[mt][0] = *(const bf16x8*)(qp);
        qf[mt][1] = *(const bf16x8*)(qp + 32);
    }

    f32x4 o[2][4], lsum[2];
#pragma unroll
    for (int mt = 0; mt < 2; ++mt) {
        lsum[mt] = (f32x4){0.f,0.f,0.f,0.f};
#pragma unroll
        for (int j = 0; j < 4; ++j) o[mt][j] = (f32x4){0.f,0.f,0.f,0.f};
    }

    bf16x8 ones;
#pragma unroll
    for (int i = 0; i < 8; ++i) ones[i] = (short)0x3F80;   // bf16 1.0

    const u32* mrow0 = mbits + (size_t)(b*SEQ + m0 + w2*32 + ln) * 64;
    const u32* mrow1 = mrow0 + ((size_t)16 * 64);

    // K/V staging: one 16B shot per thread per tile (512 thr x 16B = 8KB)
    const int lr = lane >> 3;
    const int lc = (lane & 7) ^ lr;                      // XOR-swizzled chunk
    const u16* gK = kw + hbase + (size_t)(wv*8 + lr) * 64 + lc*8;
    const u16* gV = vt + hbase + (size_t)(wv*8 + lr) * SEQ + lc*8;
    u16* lK = sK + wv * 512;
    u16* lV = sV + wv * 512;

    // Per-lane LDS base addresses; all ds_reads fold to base + immediate.
    const int c0 = (quad ^ (ln & 7)) * 8;
    const u16* a1 = smem + ln*64 + c0;          // lo chunk
    const u16* a2 = smem + ln*64 + (c0 ^ 32);   // hi chunk
    const u16* aK1 = a1 + g*2048;               // K rows of this n-half
    const u16* aK2 = a2 + g*2048;
    const u16* aV  = (g ? a2 : a1) + 16384;     // sigma vf for this n-half
    const int  msh = g*8 + quad;                // mask pre-shift

    // prologue: tiles 0 and 1 -> bufs 0, 1 (4 VMEM/tile: K, V, m0, m1)
    gl_lds16(gK, lK);
    gl_lds16(gV, lV);
    uint2 wA0 = *(const uint2*)(mrow0);
    uint2 wA1 = *(const uint2*)(mrow1);
    gl_lds16(gK + 4096, lK + 4096);
    gl_lds16(gV + 64,   lV + 4096);
    uint2 wB0 = *(const uint2*)(mrow0 + 2);
    uint2 wB1 = *(const uint2*)(mrow1 + 2);

    for (int mi = 0; mi < 8; ++mi) {
#pragma unroll
        for (int u = 0; u < 4; ++u) {
            const int bc = u;                 // read buf  = it & 3 = u
            const int wb = (u + 2) & 3;       // write buf = (it+2) & 3
            wbar_vm4();                       // drain tile it's 4 loads only
            int pidx = (mi*4 + u + 2) & 31;   // wrap keeps waitcnt uniform
            gl_lds16(gK + (size_t)pidx * 4096, lK + wb*4096);
            gl_lds16(gV + pidx * 64,           lV + wb*4096);
            uint2 wC0 = *(const uint2*)(mrow0 + pidx*2);
            uint2 wC1 = *(const uint2*)(mrow1 + pidx*2);

            // S^T = K Q^T on this wave's n-half (2 n-tiles x 2 m-tiles)
            f32x4 s4[2][2];
            __builtin_amdgcn_s_setprio(1);
#pragma unroll
            for (int ct2 = 0; ct2 < 2; ++ct2) {
                bf16x8 k0 = *(const bf16x8*)(aK1 + bc*4096 + ct2*1024);
                bf16x8 k1 = *(const bf16x8*)(aK2 + bc*4096 + ct2*1024);
#pragma unroll
                for (int mt = 0; mt < 2; ++mt) {
                    f32x4 zz = (f32x4){0.f, 0.f, 0.f, 0.f};
                    zz = __builtin_amdgcn_mfma_f32_16x16x32_bf16(k0, qf[mt][0], zz, 0, 0, 0);
                    zz = __builtin_amdgcn_mfma_f32_16x16x32_bf16(k1, qf[mt][1], zz, 0, 0, 0);
                    s4[mt][ct2] = zz;
                }
            }
            __builtin_amdgcn_s_setprio(0);

            // p = exp2(s) & keep-mask -> one packed bf16 P fragment per mt.
            bf16x8 pfm[2];
#pragma unroll
            for (int mt = 0; mt < 2; ++mt) {
                u32 wx = mt ? wA1.x : wA0.x;
                u32 wy = mt ? wA1.y : wA0.y;
                u32 l0 = ~(wx >> msh);
                u32 l1 = ~(wy >> msh);
                u32 P[4];
#pragma unroll
                for (int ct2 = 0; ct2 < 2; ++ct2) {
                    float p[4];
                    p[0] = mask_exp2(s4[mt][ct2][0], l0, ct2*4);
                    p[1] = mask_exp2(s4[mt][ct2][1], l0, 16 + ct2*4);
                    p[2] = mask_exp2(s4[mt][ct2][2], l1, ct2*4);
                    p[3] = mask_exp2(s4[mt][ct2][3], l1, 16 + ct2*4);
                    P[ct2*2]     = pk2bf(p[0], p[1]);
                    P[ct2*2 + 1] = pk2bf(p[2], p[3]);
                }
                memcpy(&pfm[mt], P, 16);
            }

            // O += P V ; lsum += P * ones. V frag loaded ONCE per ct,
            // shared by both m-tiles (sigma-matched b128, conflict-free).
            __builtin_amdgcn_s_setprio(1);
            lsum[0] = __builtin_amdgcn_mfma_f32_16x16x32_bf16(pfm[0], ones, lsum[0], 0, 0, 0);
            lsum[1] = __builtin_amdgcn_mfma_f32_16x16x32_bf16(pfm[1], ones, lsum[1], 0, 0, 0);
#pragma unroll
            for (int ct = 0; ct < 4; ++ct) {
                bf16x8 vf = *(const bf16x8*)(aV + bc*4096 + ct*1024);
                o[0][ct] = __builtin_amdgcn_mfma_f32_16x16x32_bf16(pfm[0], vf, o[0][ct], 0, 0, 0);
                o[1][ct] = __builtin_amdgcn_mfma_f32_16x16x32_bf16(pfm[1], vf, o[1][ct], 0, 0, 0);
            }
            __builtin_amdgcn_s_setprio(0);

            wA0 = wB0; wA1 = wB1;
            wB0 = wC0; wB1 = wC1;
        }
    }
    vm_drain();       // in-flight gl_lds must not land after LDS is reused
    __syncthreads();  // all waves done with sK/sV before reuse as sO

    // n-half combine: g==1 writes partial O (pitch 68) + lsum; g==0 sums,
    // normalizes, stores. One-time cost.
    float* sO  = (float*)smem;                  // 128 x 68 fp32 = 34816 B
    float* sLs = (float*)((char*)smem + 34816); // 128 fp32
    if (g == 1) {
#pragma unroll
        for (int mt = 0; mt < 2; ++mt)
#pragma unroll
            for (int i = 0; i < 4; ++i) {
                int lm = w2*32 + mt*16 + quad*4 + i;
                sLs[lm] = lsum[mt][i];
#pragma unroll
                for (int ct = 0; ct < 4; ++ct)
                    sO[lm*68 + ct*16 + ln] = o[mt][ct][i];
            }
    }
    __syncthreads();
    if (g == 0) {
#pragma unroll
        for (int mt = 0; mt < 2; ++mt)
#pragma unroll
            for (int i = 0; i < 4; ++i) {
                int lm = w2*32 + mt*16 + quad*4 + i;
                float inv = 1.f / (lsum[mt][i] + sLs[lm]);
                int m = m0 + lm;
                size_t base = ((size_t)(b * SEQ + m) << 10) + (bh & 15) * 64;
#pragma unroll
                for (int ct = 0; ct < 4; ++ct)
                    ctx[base + ct*16 + ln] =
                        f2bf((o[mt][ct][i] + sO[lm*68 + ct*16 + ln]) * inv);
            }
    }
}

// ---------------------------------------------------------------------------
extern "C" void kernel_launch(void* const* d_in, const int* in_sizes, int n_in,
                              void* d_out, int out_size, void* d_ws, size_t ws_size,
                              hipStream_t stream) {
    const float* q    = (const float*)d_in[0];
    const float* k    = (const float*)d_in[1];
    const float* v    = (const float*)d_in[2];
    const int*   mask = (const int*)d_in[3];
    const float* Wq   = (const float*)d_in[4];
    const float* Wk   = (const float*)d_in[5];
    const float* Wv   = (const float*)d_in[6];
    const float* Wo   = (const float*)d_in[7];
    float* out = (float*)d_out;

    char* ws = (char*)d_ws;
    const size_t SZH = (size_t)NB * SEQ * DM * 2;       // 8 MiB
    const size_t SZW = (size_t)DM * DM * 2;             // 2 MiB
    u16* qw   = (u16*)(ws);
    u16* kw   = (u16*)(ws + SZH);
    u16* vt   = (u16*)(ws + 2*SZH);
    u16* ctx  = (u16*)(ws + 3*SZH);
    u16* vb   = ctx;                                    // v bf16 (dead before ctx)
    u32* mbits= (u32*)(ws + 4*SZH);                     // 1 MiB
    u16* qb   = (u16*)(ws + 4*SZH + (1u<<20));
    u16* kb   = (u16*)(ws + 4*SZH + (1u<<20) + SZH);
    u16* Wqb  = (u16*)(ws + 4*SZH + (1u<<20) + 2*SZH);
    u16* Wkb  = (u16*)((char*)Wqb + SZW);
    u16* Wvb  = (u16*)((char*)Wqb + 2*SZW);
    u16* Wob  = (u16*)((char*)Wqb + 3*SZW);

    const float CSC = 0.18033688011112042f;             // 0.125 * log2(e)

    CvtArgs ca;
    ca.s[0]=q;  ca.d[0]=qb;  ca.scale[0]=1.f;
    ca.s[1]=k;  ca.d[1]=kb;  ca.scale[1]=1.f;
    ca.s[2]=v;  ca.d[2]=vb;  ca.scale[2]=1.f;
    ca.s[3]=Wq; ca.d[3]=Wqb; ca.scale[3]=CSC;
    ca.s[4]=Wk; ca.d[4]=Wkb; ca.scale[4]=1.f;
    ca.s[5]=Wv; ca.d[5]=Wvb; ca.scale[5]=1.f;
    ca.s[6]=Wo; ca.d[6]=Wob; ca.scale[6]=1.f;
    int st[8] = {0, 2048, 4096, 6144, 6656, 7168, 7680, 8192};
    for (int i = 0; i < 8; ++i) ca.start[i] = st[i];
    ca.mask  = mask;
    ca.mbits = mbits;
    // merged cvt (bid<8192) + maskpack (bid>=8192, 4 ints/thread)
    cvt_kernel<<<dim3(16384), dim3(256), 0, stream>>>(ca);

    QKVArgs ga;
    ga.A[0]=qb;  ga.B[0]=Wqb; ga.Y[0]=qw;
    ga.A[1]=kb;  ga.B[1]=Wkb; ga.Y[1]=kw;
    ga.A[2]=Wvb; ga.B[2]=vb;  ga.Y[2]=vt;
    // 256x256 deep-phase: 64 tiles per z (z<2: 16r x 4c; z=2: 4r x 16c)
    gemm_qkv256<<<dim3(64, 3), dim3(512), 0, stream>>>(ga);

    attn_kernel<<<dim3(SEQ/128, NB*NH), dim3(512), 0, stream>>>(qw, kw, vt, mbits, ctx);

    gemm_out<<<dim3(64, 8), dim3(256), 0, stream>>>(ctx, Wob, out);
}

// Round 13
// 240.617 us; speedup vs baseline: 1.0480x; 1.0204x over previous
//
#include <hip/hip_runtime.h>
#include <hip/hip_bf16.h>
#include <stdint.h>
#include <string.h>

// B=2, S=2048, D_MODEL=1024, H=16, Dh=64
#define SEQ   2048
#define DM    1024
#define NH    16
#define NB    2

typedef __attribute__((ext_vector_type(8))) short bf16x8;
typedef __attribute__((ext_vector_type(4))) float f32x4;
typedef unsigned short u16;
typedef unsigned int   u32;

__device__ __forceinline__ u16 f2bf(float f) {
    u32 u = __float_as_uint(f);
    u += 0x7FFF + ((u >> 16) & 1);   // RNE
    return (u16)(u >> 16);
}
__device__ __forceinline__ u32 pk2bf(float a, float b) {
    __hip_bfloat162 p = __float22bfloat162_rn(make_float2(a, b));
    u32 u; memcpy(&u, &p, 4); return u;
}
__device__ __forceinline__ float fexp2(float x) {
#if __has_builtin(__builtin_amdgcn_exp2f)
    return __builtin_amdgcn_exp2f(x);
#else
    return exp2f(x);
#endif
}
// exp2 with mask folded in: keep-bit (from inverted mask word) sign-extended
// and ANDed into the result. masked -> exactly 0.0f (== exp2(-1e9) path).
__device__ __forceinline__ float mask_exp2(float s, u32 lsel, int pos) {
#if __has_builtin(__builtin_amdgcn_sbfe)
    u32 keep = (u32)__builtin_amdgcn_sbfe((int)lsel, pos, 1);
#else
    u32 keep = (u32)((int)(lsel << (31 - pos)) >> 31);
#endif
    return __uint_as_float(__float_as_uint(fexp2(s)) & keep);
}
// async global->LDS, 16B/lane; LDS dest = wave-uniform base + lane*16
__device__ __forceinline__ void gl_lds16(const void* g, void* l) {
    __builtin_amdgcn_global_load_lds(
        (const __attribute__((address_space(1))) u32*)g,
        (__attribute__((address_space(3))) u32*)l, 16, 0, 0);
}
// Raw barrier WITHOUT vmcnt(0) drain: wait until only N newest VMEM ops
// remain in flight, then s_barrier. "memory" clobber pins ordering.
__device__ __forceinline__ void wbar_vm2() { asm volatile("s_waitcnt vmcnt(2)\ns_barrier" ::: "memory"); }
__device__ __forceinline__ void wbar_vm4() { asm volatile("s_waitcnt vmcnt(4)\ns_barrier" ::: "memory"); }
__device__ __forceinline__ void bar()      { asm volatile("s_barrier" ::: "memory"); }
__device__ __forceinline__ void vm_drain() { asm volatile("s_waitcnt vmcnt(0)" ::: "memory"); }

// ---------------------------------------------------------------------------
// Merged fp32->bf16 convert + maskpack (one launch; R6-validated -15us).
// bid < 8192: bulk cvt; Wq pre-scaled by 0.125*log2(e) (exp2 domain).
// bid >= 8192: maskpack, 4 ints/thread via uint4 + 4x __ballot.
// Bit layout (ballot-native, consumed by attn): per 64-n tile one u64
// (uint2); halfword i holds bits for n%4==i, bit index = (n%64)>>2.
// ---------------------------------------------------------------------------
struct CvtArgs {
    const float* s[7];
    u16* d[7];
    float scale[7];
    int start[8];
    const int* mask;
    u32* mbits;
};
__global__ __launch_bounds__(256) void cvt_kernel(CvtArgs a) {
    int bid = blockIdx.x;
    int tid = threadIdx.x;
    if (bid >= 8192) {
        int widx = (bid - 8192) * 256 + tid;          // uint4 index
        uint4 v = ((const uint4*)a.mask)[widx];
        unsigned long long b0 = __ballot(v.x != 0);
        unsigned long long b1 = __ballot(v.y != 0);
        unsigned long long b2 = __ballot(v.z != 0);
        unsigned long long b3 = __ballot(v.w != 0);
        int lane = tid & 63;
        if (lane < 4) {
            int sh = lane * 16;
            u32 lo = (u32)((b0 >> sh) & 0xFFFF) | ((u32)((b1 >> sh) & 0xFFFF) << 16);
            u32 hi = (u32)((b2 >> sh) & 0xFFFF) | ((u32)((b3 >> sh) & 0xFFFF) << 16);
            size_t N = (size_t)(bid - 8192) * 1024 + (size_t)(tid >> 6) * 256
                     + (size_t)lane * 64;             // global element index
            u32* dst = a.mbits + ((N >> 11) * 64 + ((N >> 6) & 31) * 2);
            *(uint2*)dst = make_uint2(lo, hi);
        }
        return;
    }
    int seg = 0;
#pragma unroll
    for (int i = 1; i < 7; ++i) if (bid >= a.start[i]) seg = i;
    float sc = a.scale[seg];
    size_t base = (size_t)(bid - a.start[seg]) * 2048 + tid * 8;
    const float4* s4 = (const float4*)(a.s[seg] + base);
    float4 x = s4[0], y = s4[1];
    u32 r[4];
    r[0] = pk2bf(x.x*sc, x.y*sc); r[1] = pk2bf(x.z*sc, x.w*sc);
    r[2] = pk2bf(y.x*sc, y.y*sc); r[3] = pk2bf(y.z*sc, y.w*sc);
    *(uint4*)(a.d[seg] + base) = *(uint4*)r;
}

struct QKVArgs { const u16* A[3]; const u16* B[3]; u16* Y[3]; };

// ---------------------------------------------------------------------------
// 256x256 deep-phase qkv GEMM (m201-class schedule; R12-validated, passed
// refcheck with absmax unchanged): 512 thr = 8 waves (2M x 4N), BK=64, 2 LDS
// buffers (128 KB), 4 phases per K-tile. Phase p: {stage half-tile p of
// K-tile kt+1 into the dead buffer | p0: vmcnt(2)+barrier (counted drain of
// kt's 8 loads, never 0); p1-3: barrier | p0: 16x ds_read A-frags | 2x
// ds_read B-frag | setprio(1) 16 MFMA setprio(0)}.
// Race-freedom: (a) p0's stage (A-h0 region) overlaps only stragglers reading
// B-regions of the dead buffer (disjoint); (b) p1-3 stages issue after a
// barrier transitively ordering ALL reads of the dead buffer; (c) vmcnt(2)
// after issuing 2 new loads drains exactly the incoming tile's 8.
// Swizzle: phys chunk = logical ^ (row&7) on the 8-chunk/128B row (staged via
// pre-swizzled global source, read via XOR'd col) -> reads land ~2-way (free).
// ---------------------------------------------------------------------------
__global__ __launch_bounds__(512, 2) void gemm_qkv256(QKVArgs g) {
    __shared__ __align__(16) u16 smem[65536];   // 128 KB: 2 x {Ah0,Ah1,Bh0,Bh1}

    const int z  = blockIdx.y;
    const int bx = blockIdx.x;
    int rtile, ctile, mode;
    if (z == 2) { rtile = bx & 3;  ctile = bx >> 2; mode = 1; }
    else        { rtile = bx >> 2; ctile = bx & 3;  mode = 0; }
    const u16* Aa = g.A[z];
    const u16* Ba = g.B[z];
    u16*       Yy = g.Y[z];

    const int tid  = threadIdx.x;
    const int wv   = tid >> 6, lane = tid & 63;
    const int quad = lane >> 4, ln = lane & 15;
    const int wr   = wv >> 2,  wc  = wv & 3;     // 2M x 4N waves

    // staging sources: thread t covers phys chunks t and t+512 of each
    // 16KB half-tile; logical col chunk = (t&7) ^ (row&7) (involution).
    const int r0  = tid >> 3;                    // row 0..63 (load1: +64)
    const int lcq = ((tid & 7) ^ (r0 & 7)) * 8;  // u16 col offset
    const u16* srcs[4];
    srcs[0] = Aa + (size_t)(rtile*256 +       r0) * 1024 + lcq;   // A h0
    srcs[1] = Aa + (size_t)(rtile*256 + 128 + r0) * 1024 + lcq;   // A h1
    srcs[2] = Ba + (size_t)(ctile*256 +       r0) * 1024 + lcq;   // B h0
    srcs[3] = Ba + (size_t)(ctile*256 + 128 + r0) * 1024 + lcq;   // B h1

    // read pointers: phys col = (ks*32 + quad*8) ^ ((ln&7)<<3)  [u16]
    const int sw3 = (ln & 7) << 3;
    const int cs0 = (quad * 8) ^ sw3;
    const int cs1 = (32 + quad * 8) ^ sw3;
    const u16* aA  = smem + wr*8192 + ln*64 + cs0;
    const u16* aA2 = smem + wr*8192 + ln*64 + cs1;
    const u16* bB  = smem + 16384 + (wc>>1)*8192 + (wc&1)*4096 + ln*64 + cs0;
    const u16* bB2 = smem + 16384 + (wc>>1)*8192 + (wc&1)*4096 + ln*64 + cs1;

    f32x4 acc[8][4];
#pragma unroll
    for (int i = 0; i < 8; ++i)
#pragma unroll
        for (int j = 0; j < 4; ++j) acc[i][j] = (f32x4){0.f,0.f,0.f,0.f};

    // prologue: K-tile 0 -> buf0 (4 half-tiles x 2 loads)
#pragma unroll
    for (int p = 0; p < 4; ++p) {
        u16* dst = smem + p*8192 + wv*512;
        gl_lds16(srcs[p], dst);
        gl_lds16(srcs[p] + 65536, dst + 4096);
    }

    for (int kt = 0; kt < 16; ++kt) {
        const int D  = (kt & 1) << 15;           // read buffer (u16 offset)
        const int Dp = D ^ 32768;                // write buffer
        const int pk = (kt + 1) & 15;            // wrap keeps waitcnt uniform
        bf16x8 af[8][2];
#pragma unroll
        for (int p = 0; p < 4; ++p) {
            u16* dst = smem + Dp + p*8192 + wv*512;
            gl_lds16(srcs[p] + pk*64, dst);
            gl_lds16(srcs[p] + pk*64 + 65536, dst + 4096);
            if (p == 0) wbar_vm2(); else bar();
            if (p == 0) {
#pragma unroll
                for (int mf = 0; mf < 8; ++mf) {
                    af[mf][0] = *(const bf16x8*)(aA  + D + mf*1024);
                    af[mf][1] = *(const bf16x8*)(aA2 + D + mf*1024);
                }
            }
            bf16x8 b0 = *(const bf16x8*)(bB  + D + p*1024);
            bf16x8 b1 = *(const bf16x8*)(bB2 + D + p*1024);
            __builtin_amdgcn_s_setprio(1);
#pragma unroll
            for (int mf = 0; mf < 8; ++mf) {
                acc[mf][p] = __builtin_amdgcn_mfma_f32_16x16x32_bf16(
                    af[mf][0], b0, acc[mf][p], 0, 0, 0);
                acc[mf][p] = __builtin_amdgcn_mfma_f32_16x16x32_bf16(
                    af[mf][1], b1, acc[mf][p], 0, 0, 0);
            }
            __builtin_amdgcn_s_setprio(0);
        }
    }
    vm_drain();   // trailing wrap-stages must not outlive the kernel

#pragma unroll
    for (int mf = 0; mf < 8; ++mf)
#pragma unroll
        for (int nf = 0; nf < 4; ++nf)
#pragma unroll
            for (int i = 0; i < 4; ++i) {
                int R = rtile*256 + wr*128 + mf*16 + quad*4 + i;
                int C = ctile*256 + wc*64 + nf*16 + ln;
                float val = acc[mf][nf][i];
                if (mode == 0) {
                    int b = R >> 11, s = R & 2047, h = C >> 6, d = C & 63;
                    Yy[((size_t)((b*NH + h) * SEQ + s) << 6) + d] = f2bf(val);
                } else {
                    int h = R >> 6, d = R & 63, b = C >> 11, n = C & 2047;
                    // sigma column perm within each 64-col block
                    int nl = n & 63;
                    int np = (nl & 32) | (((nl & 15) >> 2) << 3) | (nl & 3)
                           | ((nl & 16) >> 2);
                    n = (n & ~63) | np;
                    Yy[((size_t)((b*NH + h) * 64 + d) << 11) + n] = f2bf(val);
                }
            }
}

// ---------------------------------------------------------------------------
// Deep-phase 128x256 output GEMM (same R12-validated schedule class, lighter
// tile): out[R][C] = sum_k ctx[R][k]*Wo[C][k], fp32 output. 512 thr = 8 waves
// (2M x 4N), per-wave 64x64 (acc[4][4]), BK=64, 2 LDS buffers (96 KB -> 1
// block/CU; this schedule self-hides at 1/CU, proven by gemm_qkv256).
// 6 loads/K-tile staged {p0: A(2), p1: Bh0(2), p2: Bh1(2), p3: none};
// counted vmcnt(2) at p0 drains the previous tile's 6, never 0.
// Race-freedom: identical argument to gemm_qkv256 (p0 stage targets the A
// region whose last reads were at the previous p0, 3 barriers back; p1/p2
// stages issue after p0's barrier which transitively orders all reads).
// ---------------------------------------------------------------------------
__global__ __launch_bounds__(512, 2) void gemm_out256(const u16* __restrict__ A,
                                                      const u16* __restrict__ Bm,
                                                      float* __restrict__ Y) {
    __shared__ __align__(16) u16 smem[49152];   // 96 KB: 2 x {A 16K, Bh0, Bh1}

    const int bx = blockIdx.x;
    const int rtile = bx >> 2, ctile = bx & 3;   // 32 x 4 tiles of 128x256

    const int tid  = threadIdx.x;
    const int wv   = tid >> 6, lane = tid & 63;
    const int quad = lane >> 4, ln = lane & 15;
    const int wr   = wv >> 2,  wc  = wv & 3;     // 2M x 4N; per-wave 64x64

    const int r0  = tid >> 3;
    const int lcq = ((tid & 7) ^ (r0 & 7)) * 8;  // pre-swizzled source chunk
    const u16* srcs[3];
    srcs[0] = A  + (size_t)(rtile*128 +       r0) * 1024 + lcq;  // A rows
    srcs[1] = Bm + (size_t)(ctile*256 +       r0) * 1024 + lcq;  // B h0
    srcs[2] = Bm + (size_t)(ctile*256 + 128 + r0) * 1024 + lcq;  // B h1

    const int sw3 = (ln & 7) << 3;
    const int cs0 = (quad * 8) ^ sw3;
    const int cs1 = (32 + quad * 8) ^ sw3;
    const u16* aA  = smem + (wr*64 + ln)*64 + cs0;
    const u16* aA2 = smem + (wr*64 + ln)*64 + cs1;
    const u16* bB  = smem + 8192 + (wc*64 + ln)*64 + cs0;
    const u16* bB2 = smem + 8192 + (wc*64 + ln)*64 + cs1;

    f32x4 acc[4][4];
#pragma unroll
    for (int i = 0; i < 4; ++i)
#pragma unroll
        for (int j = 0; j < 4; ++j) acc[i][j] = (f32x4){0.f,0.f,0.f,0.f};

    // prologue: K-tile 0 -> buf0 (A 2 loads, Bh0 2, Bh1 2)
#pragma unroll
    for (int p = 0; p < 3; ++p) {
        u16* dst = smem + p*8192 + wv*512;
        gl_lds16(srcs[p], dst);
        gl_lds16(srcs[p] + 65536, dst + 4096);
    }

    for (int kt = 0; kt < 16; ++kt) {
        const int D  = (kt & 1) * 24576;         // read buffer (u16 offset)
        const int Dp = 24576 - D;                // write buffer
        const int pk = (kt + 1) & 15;            // wrap keeps waitcnt uniform
        bf16x8 af[4][2];
#pragma unroll
        for (int p = 0; p < 4; ++p) {
            if (p < 3) {
                u16* dst = smem + Dp + p*8192 + wv*512;
                gl_lds16(srcs[p] + pk*64, dst);
                gl_lds16(srcs[p] + pk*64 + 65536, dst + 4096);
            }
            if (p == 0) wbar_vm2(); else bar();
            if (p == 0) {
#pragma unroll
                for (int mf = 0; mf < 4; ++mf) {
                    af[mf][0] = *(const bf16x8*)(aA  + D + mf*1024);
                    af[mf][1] = *(const bf16x8*)(aA2 + D + mf*1024);
                }
            }
            bf16x8 b0 = *(const bf16x8*)(bB  + D + p*1024);
            bf16x8 b1 = *(const bf16x8*)(bB2 + D + p*1024);
            __builtin_amdgcn_s_setprio(1);
#pragma unroll
            for (int mf = 0; mf < 4; ++mf) {
                acc[mf][p] = __builtin_amdgcn_mfma_f32_16x16x32_bf16(
                    af[mf][0], b0, acc[mf][p], 0, 0, 0);
                acc[mf][p] = __builtin_amdgcn_mfma_f32_16x16x32_bf16(
                    af[mf][1], b1, acc[mf][p], 0, 0, 0);
            }
            __builtin_amdgcn_s_setprio(0);
        }
    }
    vm_drain();   // trailing wrap-stages must not outlive the kernel

#pragma unroll
    for (int mf = 0; mf < 4; ++mf)
#pragma unroll
        for (int nf = 0; nf < 4; ++nf)
#pragma unroll
            for (int i = 0; i < 4; ++i) {
                int R = rtile*128 + wr*64 + mf*16 + quad*4 + i;
                int C = ctile*256 + wc*64 + nf*16 + ln;
                Y[(size_t)R * 1024 + C] = acc[mf][nf][i];
            }
}

// ---------------------------------------------------------------------------
// Flash attention v10: in-register P + producer-permuted V + 4m x 2n wave
// split. [R8: equal to v8 -> attn is VALU/issue-bound, not LDS-bound. Best
// measured variant (66.5-67.2us, 0 bank conflicts); FROZEN.]
// Per-iter VMEM = {K,V,mask0,mask1}, prefetch dist 2 -> raw barrier vmcnt(4).
// LDS: K 4x8KB | V 4x8KB = 64KB (combine reuses it after drain+sync).
// ---------------------------------------------------------------------------
__global__ __launch_bounds__(512, 4) void attn_kernel(
    const u16* __restrict__ qw,
    const u16* __restrict__ kw,
    const u16* __restrict__ vt,
    const u32* __restrict__ mbits,
    u16* __restrict__ ctx) {

    __shared__ __align__(16) u16 smem[32768];   // 64 KB: K bufs | V bufs
    u16* sK = smem;                              // bufs at bc*4096 (u16)
    u16* sV = smem + 16384;                      // byte 32768

    const int mtile = blockIdx.x;           // 0..15 (128 m-rows each)
    const int bh    = blockIdx.y;           // 0..31
    const int b     = bh >> 4;
    const int tid   = threadIdx.x;
    const int wv    = tid >> 6, lane = tid & 63;
    const int quad  = lane >> 4, ln = lane & 15;
    const int g     = wv >> 2;              // n-half: 0 -> n 0..31, 1 -> 32..63
    const int w2    = wv & 3;               // m-group (32 rows each)
    const int m0    = mtile * 128;

    const size_t hbase = (size_t)bh * SEQ * 64;

    // Q fragments (B operand of S^T): rows m = m0 + w2*32 + mt*16 + ln
    bf16x8 qf[2][2];
#pragma unroll
    for (int mt = 0; mt < 2; ++mt) {
        const u16* qp = qw + hbase + (size_t)(m0 + w2*32 + mt*16 + ln) * 64 + quad*8;
        qf[mt][0] = *(const bf16x8*)(qp);
        qf[mt][1] = *(const bf16x8*)(qp + 32);
    }

    f32x4 o[2][4], lsum[2];
#pragma unroll
    for (int mt = 0; mt < 2; ++mt) {
        lsum[mt] = (f32x4){0.f,0.f,0.f,0.f};
#pragma unroll
        for (int j = 0; j < 4; ++j) o[mt][j] = (f32x4){0.f,0.f,0.f,0.f};
    }

    bf16x8 ones;
#pragma unroll
    for (int i = 0; i < 8; ++i) ones[i] = (short)0x3F80;   // bf16 1.0

    const u32* mrow0 = mbits + (size_t)(b*SEQ + m0 + w2*32 + ln) * 64;
    const u32* mrow1 = mrow0 + ((size_t)16 * 64);

    // K/V staging: one 16B shot per thread per tile (512 thr x 16B = 8KB)
    const int lr = lane >> 3;
    const int lc = (lane & 7) ^ lr;                      // XOR-swizzled chunk
    const u16* gK = kw + hbase + (size_t)(wv*8 + lr) * 64 + lc*8;
    const u16* gV = vt + hbase + (size_t)(wv*8 + lr) * SEQ + lc*8;
    u16* lK = sK + wv * 512;
    u16* lV = sV + wv * 512;

    // Per-lane LDS base addresses; all ds_reads fold to base + immediate.
    const int c0 = (quad ^ (ln & 7)) * 8;
    const u16* a1 = smem + ln*64 + c0;          // lo chunk
    const u16* a2 = smem + ln*64 + (c0 ^ 32);   // hi chunk
    const u16* aK1 = a1 + g*2048;               // K rows of this n-half
    const u16* aK2 = a2 + g*2048;
    const u16* aV  = (g ? a2 : a1) + 16384;     // sigma vf for this n-half
    const int  msh = g*8 + quad;                // mask pre-shift

    // prologue: tiles 0 and 1 -> bufs 0, 1 (4 VMEM/tile: K, V, m0, m1)
    gl_lds16(gK, lK);
    gl_lds16(gV, lV);
    uint2 wA0 = *(const uint2*)(mrow0);
    uint2 wA1 = *(const uint2*)(mrow1);
    gl_lds16(gK + 4096, lK + 4096);
    gl_lds16(gV + 64,   lV + 4096);
    uint2 wB0 = *(const uint2*)(mrow0 + 2);
    uint2 wB1 = *(const uint2*)(mrow1 + 2);

    for (int mi = 0; mi < 8; ++mi) {
#pragma unroll
        for (int u = 0; u < 4; ++u) {
            const int bc = u;                 // read buf  = it & 3 = u
            const int wb = (u + 2) & 3;       // write buf = (it+2) & 3
            wbar_vm4();                       // drain tile it's 4 loads only
            int pidx = (mi*4 + u + 2) & 31;   // wrap keeps waitcnt uniform
            gl_lds16(gK + (size_t)pidx * 4096, lK + wb*4096);
            gl_lds16(gV + pidx * 64,           lV + wb*4096);
            uint2 wC0 = *(const uint2*)(mrow0 + pidx*2);
            uint2 wC1 = *(const uint2*)(mrow1 + pidx*2);

            // S^T = K Q^T on this wave's n-half (2 n-tiles x 2 m-tiles)
            f32x4 s4[2][2];
            __builtin_amdgcn_s_setprio(1);
#pragma unroll
            for (int ct2 = 0; ct2 < 2; ++ct2) {
                bf16x8 k0 = *(const bf16x8*)(aK1 + bc*4096 + ct2*1024);
                bf16x8 k1 = *(const bf16x8*)(aK2 + bc*4096 + ct2*1024);
#pragma unroll
                for (int mt = 0; mt < 2; ++mt) {
                    f32x4 zz = (f32x4){0.f, 0.f, 0.f, 0.f};
                    zz = __builtin_amdgcn_mfma_f32_16x16x32_bf16(k0, qf[mt][0], zz, 0, 0, 0);
                    zz = __builtin_amdgcn_mfma_f32_16x16x32_bf16(k1, qf[mt][1], zz, 0, 0, 0);
                    s4[mt][ct2] = zz;
                }
            }
            __builtin_amdgcn_s_setprio(0);

            // p = exp2(s) & keep-mask -> one packed bf16 P fragment per mt.
            bf16x8 pfm[2];
#pragma unroll
            for (int mt = 0; mt < 2; ++mt) {
                u32 wx = mt ? wA1.x : wA0.x;
                u32 wy = mt ? wA1.y : wA0.y;
                u32 l0 = ~(wx >> msh);
                u32 l1 = ~(wy >> msh);
                u32 P[4];
#pragma unroll
                for (int ct2 = 0; ct2 < 2; ++ct2) {
                    float p[4];
                    p[0] = mask_exp2(s4[mt][ct2][0], l0, ct2*4);
                    p[1] = mask_exp2(s4[mt][ct2][1], l0, 16 + ct2*4);
                    p[2] = mask_exp2(s4[mt][ct2][2], l1, ct2*4);
                    p[3] = mask_exp2(s4[mt][ct2][3], l1, 16 + ct2*4);
                    P[ct2*2]     = pk2bf(p[0], p[1]);
                    P[ct2*2 + 1] = pk2bf(p[2], p[3]);
                }
                memcpy(&pfm[mt], P, 16);
            }

            // O += P V ; lsum += P * ones. V frag loaded ONCE per ct,
            // shared by both m-tiles (sigma-matched b128, conflict-free).
            __builtin_amdgcn_s_setprio(1);
            lsum[0] = __builtin_amdgcn_mfma_f32_16x16x32_bf16(pfm[0], ones, lsum[0], 0, 0, 0);
            lsum[1] = __builtin_amdgcn_mfma_f32_16x16x32_bf16(pfm[1], ones, lsum[1], 0, 0, 0);
#pragma unroll
            for (int ct = 0; ct < 4; ++ct) {
                bf16x8 vf = *(const bf16x8*)(aV + bc*4096 + ct*1024);
                o[0][ct] = __builtin_amdgcn_mfma_f32_16x16x32_bf16(pfm[0], vf, o[0][ct], 0, 0, 0);
                o[1][ct] = __builtin_amdgcn_mfma_f32_16x16x32_bf16(pfm[1], vf, o[1][ct], 0, 0, 0);
            }
            __builtin_amdgcn_s_setprio(0);

            wA0 = wB0; wA1 = wB1;
            wB0 = wC0; wB1 = wC1;
        }
    }
    vm_drain();       // in-flight gl_lds must not land after LDS is reused
    __syncthreads();  // all waves done with sK/sV before reuse as sO

    // n-half combine: g==1 writes partial O (pitch 68) + lsum; g==0 sums,
    // normalizes, stores. One-time cost.
    float* sO  = (float*)smem;                  // 128 x 68 fp32 = 34816 B
    float* sLs = (float*)((char*)smem + 34816); // 128 fp32
    if (g == 1) {
#pragma unroll
        for (int mt = 0; mt < 2; ++mt)
#pragma unroll
            for (int i = 0; i < 4; ++i) {
                int lm = w2*32 + mt*16 + quad*4 + i;
                sLs[lm] = lsum[mt][i];
#pragma unroll
                for (int ct = 0; ct < 4; ++ct)
                    sO[lm*68 + ct*16 + ln] = o[mt][ct][i];
            }
    }
    __syncthreads();
    if (g == 0) {
#pragma unroll
        for (int mt = 0; mt < 2; ++mt)
#pragma unroll
            for (int i = 0; i < 4; ++i) {
                int lm = w2*32 + mt*16 + quad*4 + i;
                float inv = 1.f / (lsum[mt][i] + sLs[lm]);
                int m = m0 + lm;
                size_t base = ((size_t)(b * SEQ + m) << 10) + (bh & 15) * 64;
#pragma unroll
                for (int ct = 0; ct < 4; ++ct)
                    ctx[base + ct*16 + ln] =
                        f2bf((o[mt][ct][i] + sO[lm*68 + ct*16 + ln]) * inv);
            }
    }
}

// ---------------------------------------------------------------------------
extern "C" void kernel_launch(void* const* d_in, const int* in_sizes, int n_in,
                              void* d_out, int out_size, void* d_ws, size_t ws_size,
                              hipStream_t stream) {
    const float* q    = (const float*)d_in[0];
    const float* k    = (const float*)d_in[1];
    const float* v    = (const float*)d_in[2];
    const int*   mask = (const int*)d_in[3];
    const float* Wq   = (const float*)d_in[4];
    const float* Wk   = (const float*)d_in[5];
    const float* Wv   = (const float*)d_in[6];
    const float* Wo   = (const float*)d_in[7];
    float* out = (float*)d_out;

    char* ws = (char*)d_ws;
    const size_t SZH = (size_t)NB * SEQ * DM * 2;       // 8 MiB
    const size_t SZW = (size_t)DM * DM * 2;             // 2 MiB
    u16* qw   = (u16*)(ws);
    u16* kw   = (u16*)(ws + SZH);
    u16* vt   = (u16*)(ws + 2*SZH);
    u16* ctx  = (u16*)(ws + 3*SZH);
    u16* vb   = ctx;                                    // v bf16 (dead before ctx)
    u32* mbits= (u32*)(ws + 4*SZH);                     // 1 MiB
    u16* qb   = (u16*)(ws + 4*SZH + (1u<<20));
    u16* kb   = (u16*)(ws + 4*SZH + (1u<<20) + SZH);
    u16* Wqb  = (u16*)(ws + 4*SZH + (1u<<20) + 2*SZH);
    u16* Wkb  = (u16*)((char*)Wqb + SZW);
    u16* Wvb  = (u16*)((char*)Wqb + 2*SZW);
    u16* Wob  = (u16*)((char*)Wqb + 3*SZW);

    const float CSC = 0.18033688011112042f;             // 0.125 * log2(e)

    CvtArgs ca;
    ca.s[0]=q;  ca.d[0]=qb;  ca.scale[0]=1.f;
    ca.s[1]=k;  ca.d[1]=kb;  ca.scale[1]=1.f;
    ca.s[2]=v;  ca.d[2]=vb;  ca.scale[2]=1.f;
    ca.s[3]=Wq; ca.d[3]=Wqb; ca.scale[3]=CSC;
    ca.s[4]=Wk; ca.d[4]=Wkb; ca.scale[4]=1.f;
    ca.s[5]=Wv; ca.d[5]=Wvb; ca.scale[5]=1.f;
    ca.s[6]=Wo; ca.d[6]=Wob; ca.scale[6]=1.f;
    int st[8] = {0, 2048, 4096, 6144, 6656, 7168, 7680, 8192};
    for (int i = 0; i < 8; ++i) ca.start[i] = st[i];
    ca.mask  = mask;
    ca.mbits = mbits;
    // merged cvt (bid<8192) + maskpack (bid>=8192, 4 ints/thread)
    cvt_kernel<<<dim3(16384), dim3(256), 0, stream>>>(ca);

    QKVArgs ga;
    ga.A[0]=qb;  ga.B[0]=Wqb; ga.Y[0]=qw;
    ga.A[1]=kb;  ga.B[1]=Wkb; ga.Y[1]=kw;
    ga.A[2]=Wvb; ga.B[2]=vb;  ga.Y[2]=vt;
    // 256x256 deep-phase: 64 tiles per z (z<2: 16r x 4c; z=2: 4r x 16c)
    gemm_qkv256<<<dim3(64, 3), dim3(512), 0, stream>>>(ga);

    attn_kernel<<<dim3(SEQ/128, NB*NH), dim3(512), 0, stream>>>(qw, kw, vt, mbits, ctx);

    // 128x256 deep-phase output GEMM: 32r x 4c tiles
    gemm_out256<<<dim3(128), dim3(512), 0, stream>>>(ctx, Wob, out);
}